// Round 2
// baseline (60.268 us; speedup 1.0000x reference)
//
#include <hip/hip_runtime.h>
#include <math.h>

#define NB_B 8
#define NB_C 256
#define NB_HW 9216          // 96*96
#define TOTPIX 73728        // 8*9216
#define NGRP (TOTPIX / 4)   // float4 pixel-groups = 18432
#define NBLK 1024           // 32*32 blocks per batch
// lower median of 9216 flat elems = sorted idx 4607 = block rank 511 (4607/9)

// ---------------- kernel 1: partial channel reduction, float4 over pixels ----
// part[chunk][pix] = sum over (256/NCH) channels of (rec-align)^2
template<int NCH>
__global__ __launch_bounds__(256, 4) void k_loss_partial(const float* __restrict__ rec,
                                                         const float* __restrict__ al,
                                                         float* __restrict__ part) {
  const int grp = blockIdx.x * 256 + threadIdx.x;       // 0..NGRP-1
  const int chunk = blockIdx.y;                          // 0..NCH-1
  constexpr int cpc = NB_C / NCH;
  const int pix = grp * 4;
  const int b = pix / NB_HW;
  const int p = pix - b * NB_HW;                         // multiple of 4
  const size_t base = (size_t)b * NB_C * NB_HW + (size_t)chunk * cpc * NB_HW + p;
  const float4* pr = (const float4*)(rec + base);
  const float4* pa = (const float4*)(al + base);
  // stride between channels in float4 units
  constexpr int CS = NB_HW / 4;

  float4 acc0 = make_float4(0.f, 0.f, 0.f, 0.f);
  float4 acc1 = make_float4(0.f, 0.f, 0.f, 0.f);
#pragma unroll
  for (int c = 0; c < cpc; c += 2) {
    float4 r0 = pr[(size_t)(c + 0) * CS];
    float4 a0 = pa[(size_t)(c + 0) * CS];
    float4 r1 = pr[(size_t)(c + 1) * CS];
    float4 a1 = pa[(size_t)(c + 1) * CS];
    float d;
    d = r0.x - a0.x; acc0.x = fmaf(d, d, acc0.x);
    d = r0.y - a0.y; acc0.y = fmaf(d, d, acc0.y);
    d = r0.z - a0.z; acc0.z = fmaf(d, d, acc0.z);
    d = r0.w - a0.w; acc0.w = fmaf(d, d, acc0.w);
    d = r1.x - a1.x; acc1.x = fmaf(d, d, acc1.x);
    d = r1.y - a1.y; acc1.y = fmaf(d, d, acc1.y);
    d = r1.z - a1.z; acc1.z = fmaf(d, d, acc1.z);
    d = r1.w - a1.w; acc1.w = fmaf(d, d, acc1.w);
  }
  float4 o;
  o.x = acc0.x + acc1.x;
  o.y = acc0.y + acc1.y;
  o.z = acc0.z + acc1.z;
  o.w = acc0.w + acc1.w;
  ((float4*)(part + (size_t)chunk * TOTPIX))[grp] = o;
}

// ---------------- kernel 2: fold chunks + 3x3 block means ----------------
__global__ __launch_bounds__(256) void k_blocks(const float* __restrict__ part,
                                                float* __restrict__ blocks, int nch) {
  int id = blockIdx.x * 256 + threadIdx.x;             // 0..8191
  if (id >= NB_B * NBLK) return;
  int b = id >> 10;
  int r = id & 1023;
  int bi = r >> 5, bj = r & 31;
  int base_p = (bi * 3) * 96 + bj * 3;
  float s = 0.f;
  for (int ch = 0; ch < nch; ++ch) {
    const float* lp = part + (size_t)ch * TOTPIX + (size_t)b * NB_HW + base_p;
#pragma unroll
    for (int dy = 0; dy < 3; ++dy)
#pragma unroll
      for (int dx = 0; dx < 3; ++dx)
        s += lp[dy * 96 + dx];
  }
  blocks[id] = s * (1.0f / (256.0f * 9.0f));           // mean over C then over 3x3
}

// ---------------- kernel 3: per-batch sort + stats + weighted sum ----------------
__global__ __launch_bounds__(256) void k_stats(const float* __restrict__ blocks,
                                               double* __restrict__ bsums) {
  __shared__ float s[NBLK];
  __shared__ double red[256];
  const int b = blockIdx.x;
  const int t = threadIdx.x;
  for (int i = t; i < NBLK; i += 256) s[i] = blocks[b * NBLK + i];
  __syncthreads();

  // bitonic sort ascending (1024 elems, 256 threads, 4 pairs/thread per step)
  for (int k = 2; k <= NBLK; k <<= 1) {
    for (int j = k >> 1; j > 0; j >>= 1) {
      for (int base = 0; base < NBLK; base += 256) {
        int idx = base + t;
        int ixj = idx ^ j;
        if (ixj > idx) {
          float a = s[idx], c2 = s[ixj];
          bool up = ((idx & k) == 0);
          if ((a > c2) == up) { s[idx] = c2; s[ixj] = a; }
        }
      }
      __syncthreads();
    }
  }

  // mean
  double lp = 0.0;
  for (int i = t; i < NBLK; i += 256) lp += (double)s[i];
  red[t] = lp; __syncthreads();
  for (int w = 128; w > 0; w >>= 1) { if (t < w) red[t] += red[t + w]; __syncthreads(); }
  double mean = red[0] / 1024.0;
  __syncthreads();

  // sum of squared deviations over blocks; flat variance = 9*SS/9215 (ddof=1)
  double ss = 0.0;
  for (int i = t; i < NBLK; i += 256) { double d = (double)s[i] - mean; ss += d * d; }
  red[t] = ss; __syncthreads();
  for (int w = 128; w > 0; w >>= 1) { if (t < w) red[t] += red[t + w]; __syncthreads(); }
  double var = 9.0 * red[0] / 9215.0;
  float stdv = (float)sqrt(var);
  float safe = fmaxf(stdv, 1e-3f);
  float med = s[511];                                  // lower median of the 9x-repeated flat
  __syncthreads();

  // weighted sum: each block contributes 9 * v * (1 + 2*sigmoid((v-med)/safe))
  double wsum = 0.0;
  for (int i = t; i < NBLK; i += 256) {
    float v = s[i];
    float z = (v - med) / safe;
    float sig = 1.0f / (1.0f + expf(-z));
    wsum += (double)(9.0f * v) * (double)(1.0f + 2.0f * sig);
  }
  red[t] = wsum; __syncthreads();
  for (int w = 128; w > 0; w >>= 1) { if (t < w) red[t] += red[t + w]; __syncthreads(); }
  if (t == 0) bsums[b] = red[0];
}

// ---------------- kernel 4: combine batches ----------------
__global__ void k_final(const double* __restrict__ bsums, float* __restrict__ out) {
  if (threadIdx.x == 0 && blockIdx.x == 0) {
    double st = 0.0;
    for (int b = 0; b < NB_B; ++b) st += bsums[b];
    out[0] = (float)(st / (double)TOTPIX);
  }
}

extern "C" void kernel_launch(void* const* d_in, const int* in_sizes, int n_in,
                              void* d_out, int out_size, void* d_ws, size_t ws_size,
                              hipStream_t stream) {
  const float* rec = (const float*)d_in[0];
  const float* al  = (const float*)d_in[1];
  float* out = (float*)d_out;
  char* ws = (char*)d_ws;

  // ws layout: part[nch][73728] f32 | blocks[8192] f32 | bsums[8] f64
  const size_t need16 = (size_t)16 * TOTPIX * 4 + (size_t)NB_B * NBLK * 4 + 64;
  const int nch = (ws_size >= need16) ? 16 : 4;

  float*  part   = (float*)ws;
  float*  blocks = (float*)(ws + (size_t)nch * TOTPIX * 4);
  double* bsums  = (double*)(ws + (size_t)nch * TOTPIX * 4 + (size_t)NB_B * NBLK * 4);

  if (nch == 16)
    k_loss_partial<16><<<dim3(NGRP / 256, 16), 256, 0, stream>>>(rec, al, part);
  else
    k_loss_partial<4><<<dim3(NGRP / 256, 4), 256, 0, stream>>>(rec, al, part);

  k_blocks<<<(NB_B * NBLK + 255) / 256, 256, 0, stream>>>(part, blocks, nch);
  k_stats<<<NB_B, 256, 0, stream>>>(blocks, bsums);
  k_final<<<1, 64, 0, stream>>>(bsums, out);
}